// Round 14
// baseline (52.679 us; speedup 1.0000x reference)
//
#include <hip/hip_runtime.h>
#include <hip/hip_bf16.h>

// ANI-1 per-species MLP, v14: v13 (stage-once bf16 X, barrier-free L0) with
// the XLD bug fixed (was 200 for a 384-wide row -> row overlap -> absmax 2.3).
// XLD=392 (384+8 pad: rows shift 4 banks -> 2-way conflicts = free).
// Single 50176B LDS region, phase-aliased:
//   X[0..50176) -> Y0[0..21504) -> Y1[21504..38912) -> Y2[0..13312)
//   red[38912..40960); each alias protected by a barrier (6 total).
// 3 blocks/CU (24 waves/CU), waves_per_eu(6,6) -> 84-VGPR budget.
// Block = 512 thr (8 waves: 2 M-grp x 4 N-grp), grid = 1024 (atom, half).

typedef float f32x4 __attribute__((ext_vector_type(4)));
typedef short s16x8 __attribute__((ext_vector_type(8)));

#define NMOL   128
#define NATOM  512
#define AEV    384
#define MT     64               // molecules per block
#define XLD    392              // bf16 ld for X (384 + 8 pad)
#define Y0LD   168
#define Y1LD   136
#define Y2LD   104

// ushort offsets within the shared region
#define Y1_OFF 10752            // byte 21504
#define RED_OFF 19456           // byte 38912

// Wp element offsets (bf16 units)
#define PL0    61440            // 160*384
#define PL1    20480            // 128*160
#define PL2    12288            // 96*128
#define BASE0  0
#define BASE1  245760           // 4*PL0
#define BASE2  327680           // BASE1 + 4*PL1
#define WP_BYTE_OFF 262144      // partial buffer (512*128*4) first in d_ws

__device__ __forceinline__ ushort f2bf(float f) {   // RTN-even
    uint u = __float_as_uint(f);
    return (ushort)((u + 0x7fffu + ((u >> 16) & 1u)) >> 16);
}
__device__ __forceinline__ float bf2f(ushort h) {
    return __uint_as_float(((uint)h) << 16);
}
__device__ __forceinline__ float celu_f(float v) {
    return fmaxf(v, 0.0f) + fminf(0.1f * (__expf(10.0f * v) - 1.0f), 0.0f);
}
__device__ __forceinline__ uint pk2bf(float x, float y) {   // v_cvt_pk_bf16_f32
    __hip_bfloat162 h2;
    h2.x = __float2bfloat16(x);
    h2.y = __float2bfloat16(y);
    return *(uint*)&h2;
}

// ---- prep: W0..W2 fp32 -> bf16 in MFMA-B-fragment order, 8 elems/thread ----
__global__ __launch_bounds__(256) void prep_kernel(
    const float* __restrict__ W0, const float* __restrict__ W1,
    const float* __restrict__ W2, ushort* __restrict__ Wp)
{
    const int idx = blockIdx.x * 256 + threadIdx.x;   // grid = 47104 (x8 elems)
    int n, k0, KS;
    size_t base;
    const float* src;
    if (idx < 30720) {                        // L0: [4][160][384]
        const int s = idx / 7680, r = idx % 7680;
        n = r / 48; k0 = (r % 48) * 8; KS = 12;
        src = W0 + (size_t)idx * 8;
        base = BASE0 + (size_t)s * PL0;
    } else if (idx < 40960) {                 // L1: [4][128][160]
        const int i2 = idx - 30720;
        const int s = i2 / 2560, r = i2 % 2560;
        n = r / 20; k0 = (r % 20) * 8; KS = 5;
        src = W1 + (size_t)i2 * 8;
        base = BASE1 + (size_t)s * PL1;
    } else {                                  // L2: [4][96][128]
        const int i2 = idx - 40960;
        const int s = i2 / 1536, r = i2 % 1536;
        n = r / 16; k0 = (r % 16) * 8; KS = 4;
        src = W2 + (size_t)i2 * 8;
        base = BASE2 + (size_t)s * PL2;
    }
    const float4 v0 = *(const float4*)(src);
    const float4 v1 = *(const float4*)(src + 4);
    const size_t fo = (size_t)((((n >> 4) * KS + (k0 >> 5)) * 64
                                + ((k0 & 31) >> 3) * 16 + (n & 15)) * 8);
    uint4 w;
    w.x = pk2bf(v0.x, v0.y);
    w.y = pk2bf(v0.z, v0.w);
    w.z = pk2bf(v1.x, v1.y);
    w.w = pk2bf(v1.z, v1.w);
    *(uint4*)(Wp + base + fo) = w;
}

__global__ __attribute__((amdgpu_flat_work_group_size(512, 512),
                          amdgpu_waves_per_eu(6, 6)))
void ani_mfma_kernel(
    const float* __restrict__ aev, const int* __restrict__ species,
    const ushort* __restrict__ Wp,
    const float* __restrict__ b0, const float* __restrict__ b1,
    const float* __restrict__ b2,
    const float* __restrict__ W3, const float* __restrict__ b3,
    float* __restrict__ partial)
{
    __shared__ __align__(16) ushort smem[MT * XLD];   // 50176 B, phase-aliased

    const int bid  = blockIdx.x;
    const int a    = bid >> 1;          // atom
    const int half = bid & 1;           // molecule half
    const int tid  = threadIdx.x;
    const int lane = tid & 63;
    const int wid  = tid >> 6;
    const int mgrp = wid >> 2;          // 0..1 (32-row groups)
    const int ngrp = wid & 3;           // 0..3
    const bool has3 = (ngrp < 2);       // L0 nf=ngrp+8<10; L2 nf=ngrp+4<6

    const int s = species[a];
    const ushort* Bh0 = Wp + BASE0 + (size_t)s * PL0;
    const ushort* Bh1 = Wp + BASE1 + (size_t)s * PL1;
    const ushort* Bh2 = Wp + BASE2 + (size_t)s * PL2;
    const float* b0s = b0 + s * 160;
    const float* b1s = b1 + s * 128;
    const float* b2s = b2 + s * 96;
    const float* w3s = W3 + s * 96;
    const float  bb3 = b3[s];

    ushort* X     = smem;               // [64][392]
    ushort* y0buf = smem;               // [64][168]  (over dead X, after bar)
    ushort* y1buf = smem + Y1_OFF;      // [64][136]  (over dead X tail)
    ushort* y2buf = smem;               // [64][104]  (over dead Y0)

    const f32x4 zero = {0.f, 0.f, 0.f, 0.f};

    // ---- stage X once: thread = (row tid>>3, col-block tid&7) ----
    {
        const int srow = tid >> 3;          // 0..63
        const int scol = tid & 7;           // 0..7
        const float* sp = aev + ((size_t)(half * MT + srow) * NATOM + a) * AEV
                          + scol * 8;
        float4 rv[12];
        #pragma unroll
        for (int jp = 0; jp < 6; ++jp) {
            rv[2 * jp]     = *(const float4*)(sp + jp * 64);
            rv[2 * jp + 1] = *(const float4*)(sp + jp * 64 + 4);
        }
        ushort* xd = X + srow * XLD + scol * 8;
        #pragma unroll
        for (int jp = 0; jp < 6; ++jp) {
            uint4 w;
            w.x = pk2bf(rv[2 * jp].x,     rv[2 * jp].y);
            w.y = pk2bf(rv[2 * jp].z,     rv[2 * jp].w);
            w.z = pk2bf(rv[2 * jp + 1].x, rv[2 * jp + 1].y);
            w.w = pk2bf(rv[2 * jp + 1].z, rv[2 * jp + 1].w);
            *(uint4*)(xd + jp * 64) = w;
        }
    }
    __syncthreads();                                   // (1) X published

    // ---- L0: 384 -> 160, 12 gks fully unrolled, NO inner barriers ----
    f32x4 acc[2][3];
    #pragma unroll
    for (int mf = 0; mf < 2; ++mf)
        #pragma unroll
        for (int ti = 0; ti < 3; ++ti) acc[mf][ti] = zero;
    {
        const ushort* arow0 = X + (mgrp * 32 + (lane & 15)) * XLD + (lane >> 4) * 8;
        #pragma unroll
        for (int gks = 0; gks < 12; ++gks) {
            s16x8 ah[2];
            ah[0] = *(const s16x8*)(arow0 + gks * 32);
            ah[1] = *(const s16x8*)(arow0 + 16 * XLD + gks * 32);
            const s16x8 bh0 = *(const s16x8*)(
                Bh0 + ((size_t)((ngrp    ) * 12 + gks) * 64 + lane) * 8);
            const s16x8 bh1 = *(const s16x8*)(
                Bh0 + ((size_t)((ngrp + 4) * 12 + gks) * 64 + lane) * 8);
            acc[0][0] = __builtin_amdgcn_mfma_f32_16x16x32_bf16(ah[0], bh0, acc[0][0], 0, 0, 0);
            acc[1][0] = __builtin_amdgcn_mfma_f32_16x16x32_bf16(ah[1], bh0, acc[1][0], 0, 0, 0);
            acc[0][1] = __builtin_amdgcn_mfma_f32_16x16x32_bf16(ah[0], bh1, acc[0][1], 0, 0, 0);
            acc[1][1] = __builtin_amdgcn_mfma_f32_16x16x32_bf16(ah[1], bh1, acc[1][1], 0, 0, 0);
            if (has3) {
                const s16x8 bh2 = *(const s16x8*)(
                    Bh0 + ((size_t)((ngrp + 8) * 12 + gks) * 64 + lane) * 8);
                acc[0][2] = __builtin_amdgcn_mfma_f32_16x16x32_bf16(ah[0], bh2, acc[0][2], 0, 0, 0);
                acc[1][2] = __builtin_amdgcn_mfma_f32_16x16x32_bf16(ah[1], bh2, acc[1][2], 0, 0, 0);
            }
        }
    }
    __syncthreads();                                   // (2) all X reads done

    // ---- L0 epilogue -> Y0 (over X) ----
    #pragma unroll
    for (int ti = 0; ti < 3; ++ti) {
        if (ti < 2 || has3) {
            const int n = (ngrp + 4 * ti) * 16 + (lane & 15);
            const float bv = b0s[n];
            #pragma unroll
            for (int mf = 0; mf < 2; ++mf) {
                #pragma unroll
                for (int r = 0; r < 4; ++r) {
                    const int row = mgrp * 32 + mf * 16 + (lane >> 4) * 4 + r;
                    y0buf[row * Y0LD + n] = f2bf(celu_f(acc[mf][ti][r] + bv));
                }
            }
        }
    }
    __syncthreads();                                   // (3) Y0 published

    // ---- L1: 160 -> 128 (A from Y0; C -> Y1 @ +21504B, disjoint from Y0) ----
    f32x4 acc1[2][2];
    #pragma unroll
    for (int mf = 0; mf < 2; ++mf) { acc1[mf][0] = zero; acc1[mf][1] = zero; }
    {
        const ushort* arow0 = y0buf + (mgrp * 32 + (lane & 15)) * Y0LD + (lane >> 4) * 8;
        #pragma unroll
        for (int ks = 0; ks < 5; ++ks) {
            s16x8 ah[2];
            ah[0] = *(const s16x8*)(arow0 + ks * 32);
            ah[1] = *(const s16x8*)(arow0 + 16 * Y0LD + ks * 32);
            const s16x8 bh0 = *(const s16x8*)(
                Bh1 + ((size_t)((ngrp    ) * 5 + ks) * 64 + lane) * 8);
            const s16x8 bh1 = *(const s16x8*)(
                Bh1 + ((size_t)((ngrp + 4) * 5 + ks) * 64 + lane) * 8);
            acc1[0][0] = __builtin_amdgcn_mfma_f32_16x16x32_bf16(ah[0], bh0, acc1[0][0], 0, 0, 0);
            acc1[1][0] = __builtin_amdgcn_mfma_f32_16x16x32_bf16(ah[1], bh0, acc1[1][0], 0, 0, 0);
            acc1[0][1] = __builtin_amdgcn_mfma_f32_16x16x32_bf16(ah[0], bh1, acc1[0][1], 0, 0, 0);
            acc1[1][1] = __builtin_amdgcn_mfma_f32_16x16x32_bf16(ah[1], bh1, acc1[1][1], 0, 0, 0);
        }
    }

    // ---- L1 epilogue -> Y1 ----
    #pragma unroll
    for (int t = 0; t < 2; ++t) {
        const int n = (ngrp + 4 * t) * 16 + (lane & 15);
        const float bv = b1s[n];
        #pragma unroll
        for (int mf = 0; mf < 2; ++mf) {
            #pragma unroll
            for (int r = 0; r < 4; ++r) {
                const int row = mgrp * 32 + mf * 16 + (lane >> 4) * 4 + r;
                y1buf[row * Y1LD + n] = f2bf(celu_f(acc1[mf][t][r] + bv));
            }
        }
    }
    __syncthreads();                                   // (4) Y1 published; Y0 dead

    // ---- L2: 128 -> 96 (A from Y1; C -> Y2 over dead Y0, disjoint from Y1) ----
    f32x4 acc2[2][2];
    #pragma unroll
    for (int mf = 0; mf < 2; ++mf) { acc2[mf][0] = zero; acc2[mf][1] = zero; }
    {
        const ushort* arow0 = y1buf + (mgrp * 32 + (lane & 15)) * Y1LD + (lane >> 4) * 8;
        #pragma unroll
        for (int ks = 0; ks < 4; ++ks) {
            s16x8 ah[2];
            ah[0] = *(const s16x8*)(arow0 + ks * 32);
            ah[1] = *(const s16x8*)(arow0 + 16 * Y1LD + ks * 32);
            const s16x8 bh0 = *(const s16x8*)(
                Bh2 + ((size_t)((ngrp) * 4 + ks) * 64 + lane) * 8);
            acc2[0][0] = __builtin_amdgcn_mfma_f32_16x16x32_bf16(ah[0], bh0, acc2[0][0], 0, 0, 0);
            acc2[1][0] = __builtin_amdgcn_mfma_f32_16x16x32_bf16(ah[1], bh0, acc2[1][0], 0, 0, 0);
            if (has3) {
                const s16x8 bh1 = *(const s16x8*)(
                    Bh2 + ((size_t)((ngrp + 4) * 4 + ks) * 64 + lane) * 8);
                acc2[0][1] = __builtin_amdgcn_mfma_f32_16x16x32_bf16(ah[0], bh1, acc2[0][1], 0, 0, 0);
                acc2[1][1] = __builtin_amdgcn_mfma_f32_16x16x32_bf16(ah[1], bh1, acc2[1][1], 0, 0, 0);
            }
        }
    }

    // ---- L2 epilogue -> Y2 ----
    #pragma unroll
    for (int t = 0; t < 2; ++t) {
        if (t == 0 || has3) {
            const int n = (ngrp + 4 * t) * 16 + (lane & 15);   // < 96
            const float bv = b2s[n];
            #pragma unroll
            for (int mf = 0; mf < 2; ++mf) {
                #pragma unroll
                for (int r = 0; r < 4; ++r) {
                    const int row = mgrp * 32 + mf * 16 + (lane >> 4) * 4 + r;
                    y2buf[row * Y2LD + n] = f2bf(celu_f(acc2[mf][t][r] + bv));
                }
            }
        }
    }
    __syncthreads();                                   // (5) Y2 published; Y1 dead

    // ---- L3: 96 -> 1 (fp32 vector; red @ +38912B, disjoint from Y2) ----
    {
        float* red = (float*)(smem + RED_OFF);
        const int m = tid & (MT - 1);
        const int q = tid >> 6;       // 0..7, 12 inputs each
        float accv = 0.f;
        #pragma unroll
        for (int ii = 0; ii < 12; ++ii) {
            const int i = q * 12 + ii;
            accv = fmaf(w3s[i], bf2f(y2buf[m * Y2LD + i]), accv);
        }
        red[q * MT + m] = accv;
        __syncthreads();                               // (6) red published
        if (tid < MT) {
            float sm = bb3;
            #pragma unroll
            for (int qq = 0; qq < 8; ++qq) sm += red[qq * MT + tid];
            partial[(size_t)a * NMOL + half * MT + tid] = sm;
        }
    }
}

__global__ __launch_bounds__(256) void reduce_kernel(
    const float* __restrict__ partial, float* __restrict__ out)
{
    __shared__ float red[256];
    const int m = blockIdx.x;       // molecule
    const int t = threadIdx.x;
    float sv = partial[(size_t)t * NMOL + m] + partial[(size_t)(t + 256) * NMOL + m];
    red[t] = sv;
    __syncthreads();
    #pragma unroll
    for (int w = 128; w > 0; w >>= 1) {
        if (t < w) red[t] += red[t + w];
        __syncthreads();
    }
    if (t == 0) out[m] = red[0];
}

extern "C" void kernel_launch(void* const* d_in, const int* in_sizes, int n_in,
                              void* d_out, int out_size, void* d_ws, size_t ws_size,
                              hipStream_t stream) {
    const float* aev     = (const float*)d_in[0];
    const int*   species = (const int*)  d_in[1];
    const float* W0 = (const float*)d_in[2];
    const float* b0 = (const float*)d_in[3];
    const float* W1 = (const float*)d_in[4];
    const float* b1 = (const float*)d_in[5];
    const float* W2 = (const float*)d_in[6];
    const float* b2 = (const float*)d_in[7];
    const float* W3 = (const float*)d_in[8];
    const float* b3 = (const float*)d_in[9];
    float* out     = (float*)d_out;
    float* partial = (float*)d_ws;                               // 256 KiB
    ushort* Wp     = (ushort*)((char*)d_ws + WP_BYTE_OFF);       // ~0.75 MiB

    prep_kernel<<<184, 256, 0, stream>>>(W0, W1, W2, Wp);
    ani_mfma_kernel<<<NATOM * 2, 512, 0, stream>>>(aev, species, Wp,
                                                   b0, b1, b2, W3, b3, partial);
    reduce_kernel<<<NMOL, 256, 0, stream>>>(partial, out);
}